// Round 1
// baseline (591.620 us; speedup 1.0000x reference)
//
#include <hip/hip_runtime.h>
#include <hip/hip_fp16.h>
#include <cstdint>
#include <cstdio>

#define NROW 4096
#define DMODEL 1024
#define DFF_ 4096

typedef _Float16 f16;
typedef _Float16 f16x4 __attribute__((ext_vector_type(4)));
typedef _Float16 f16x8 __attribute__((ext_vector_type(8)));
typedef float f32x4 __attribute__((ext_vector_type(4)));

__device__ __forceinline__ void g2l16(const void* g, void* l) {
  __builtin_amdgcn_global_load_lds((const __attribute__((address_space(1))) void*)g,
                                   (__attribute__((address_space(3))) void*)l,
                                   16, 0, 0);
}

// ---------------- elementwise converts ----------------
__global__ __launch_bounds__(256) void cvt_f32_f16(const float* __restrict__ in,
                                                   f16* __restrict__ out, long n4) {
  for (long i = (long)blockIdx.x * blockDim.x + threadIdx.x; i < n4;
       i += (long)gridDim.x * blockDim.x) {
    float4 a = ((const float4*)in)[i];
    f16x4 h = {(f16)a.x, (f16)a.y, (f16)a.z, (f16)a.w};
    ((f16x4*)out)[i] = h;
  }
}

// k16 = f16(xe + pos); xe16 = f16(xe)
__global__ __launch_bounds__(256) void add_cvt(const float* __restrict__ xe,
                                               const float* __restrict__ pos,
                                               f16* __restrict__ k16,
                                               f16* __restrict__ xe16, long n4) {
  for (long i = (long)blockIdx.x * blockDim.x + threadIdx.x; i < n4;
       i += (long)gridDim.x * blockDim.x) {
    float4 a = ((const float4*)xe)[i];
    float4 p = ((const float4*)pos)[i];
    f16x4 k = {(f16)(a.x + p.x), (f16)(a.y + p.y), (f16)(a.z + p.z), (f16)(a.w + p.w)};
    f16x4 v = {(f16)a.x, (f16)a.y, (f16)a.z, (f16)a.w};
    ((f16x4*)k16)[i] = k;
    ((f16x4*)xe16)[i] = v;
  }
}

// ---------------- layernorm (one block per row of 1024) ----------------
// qout = f16(LN(x)*g + b + (pos ? pos : 0)); nout (optional) = f16(LN(x)*g + b)
__global__ __launch_bounds__(256) void ln_row(const float* __restrict__ x,
                                              const float* __restrict__ g,
                                              const float* __restrict__ b,
                                              const float* __restrict__ pos,
                                              f16* __restrict__ nout,
                                              f16* __restrict__ qout) {
  const int row = blockIdx.x, tid = threadIdx.x;
  const float4 xv = ((const float4*)(x + (long)row * DMODEL))[tid];
  float s = xv.x + xv.y + xv.z + xv.w;
  float ss = xv.x * xv.x + xv.y * xv.y + xv.z * xv.z + xv.w * xv.w;
  for (int o = 32; o; o >>= 1) { s += __shfl_xor(s, o); ss += __shfl_xor(ss, o); }
  __shared__ float rs[4], rss[4];
  const int wid = tid >> 6, lane = tid & 63;
  if (!lane) { rs[wid] = s; rss[wid] = ss; }
  __syncthreads();
  s = rs[0] + rs[1] + rs[2] + rs[3];
  ss = rss[0] + rss[1] + rss[2] + rss[3];
  const float mean = s * (1.f / DMODEL);
  const float var = ss * (1.f / DMODEL) - mean * mean;
  const float rstd = rsqrtf(var + 1e-5f);
  const float4 gv = ((const float4*)g)[tid];
  const float4 bv = ((const float4*)b)[tid];
  float4 nv;
  nv.x = (xv.x - mean) * rstd * gv.x + bv.x;
  nv.y = (xv.y - mean) * rstd * gv.y + bv.y;
  nv.z = (xv.z - mean) * rstd * gv.z + bv.z;
  nv.w = (xv.w - mean) * rstd * gv.w + bv.w;
  if (nout) {
    f16x4 h = {(f16)nv.x, (f16)nv.y, (f16)nv.z, (f16)nv.w};
    *(f16x4*)&nout[(long)row * DMODEL + tid * 4] = h;
  }
  float4 pv = {0.f, 0.f, 0.f, 0.f};
  if (pos) pv = ((const float4*)(pos + (long)row * DMODEL))[tid];
  f16x4 q = {(f16)(nv.x + pv.x), (f16)(nv.y + pv.y), (f16)(nv.z + pv.z), (f16)(nv.w + pv.w)};
  *(f16x4*)&qout[(long)row * DMODEL + tid * 4] = q;
}

// ---------------- row softmax (4096 cols), fp32 in -> fp16 out ----------------
__global__ __launch_bounds__(256) void softmax_row(const float* __restrict__ S,
                                                   f16* __restrict__ P) {
  const int row = blockIdx.x, tid = threadIdx.x;
  const float4* Sr = (const float4*)(S + (long)row * NROW);
  float4 v[4];
  float m = -1e30f;
#pragma unroll
  for (int i = 0; i < 4; i++) {
    v[i] = Sr[tid + i * 256];
    m = fmaxf(m, fmaxf(fmaxf(v[i].x, v[i].y), fmaxf(v[i].z, v[i].w)));
  }
  for (int o = 32; o; o >>= 1) m = fmaxf(m, __shfl_xor(m, o));
  __shared__ float red[4], red2[4];
  const int wid = tid >> 6, lane = tid & 63;
  if (!lane) red[wid] = m;
  __syncthreads();
  m = fmaxf(fmaxf(red[0], red[1]), fmaxf(red[2], red[3]));
  float sum = 0.f;
#pragma unroll
  for (int i = 0; i < 4; i++) {
    v[i].x = __expf(v[i].x - m); v[i].y = __expf(v[i].y - m);
    v[i].z = __expf(v[i].z - m); v[i].w = __expf(v[i].w - m);
    sum += v[i].x + v[i].y + v[i].z + v[i].w;
  }
  for (int o = 32; o; o >>= 1) sum += __shfl_xor(sum, o);
  if (!lane) red2[wid] = sum;
  __syncthreads();
  sum = red2[0] + red2[1] + red2[2] + red2[3];
  const float r = 1.f / sum;
  f16* Pr = P + (long)row * NROW;
#pragma unroll
  for (int i = 0; i < 4; i++) {
    f16x4 h = {(f16)(v[i].x * r), (f16)(v[i].y * r), (f16)(v[i].z * r), (f16)(v[i].w * r)};
    *(f16x4*)&Pr[(tid + i * 256) * 4] = h;
  }
}

// ---------------- fp16 transpose: in [R][C] -> out [C][R], 64x64 tiles ----------------
__global__ __launch_bounds__(256) void transpose_h(const f16* __restrict__ in,
                                                   f16* __restrict__ out, int R, int C) {
  __shared__ f16 t[64][72];
  const int tid = threadIdx.x;
  const int r0 = blockIdx.y * 64, c0 = blockIdx.x * 64;
  const int tr = tid >> 4, tc = (tid & 15) * 4;
#pragma unroll
  for (int rr = 0; rr < 4; rr++) {
    int row = rr * 16 + tr;
    f16x4 v = *(const f16x4*)&in[(long)(r0 + row) * C + c0 + tc];
    *(f16x4*)&t[row][tc] = v;
  }
  __syncthreads();
#pragma unroll
  for (int rr = 0; rr < 4; rr++) {
    int row = rr * 16 + tr;  // output row within tile = input col
    f16x4 o = {t[tc + 0][row], t[tc + 1][row], t[tc + 2][row], t[tc + 3][row]};
    *(f16x4*)&out[(long)(c0 + row) * R + r0 + tc] = o;
  }
}

// ---------------- NT GEMM: C[m,n] = sum_k A[m,k]*B[n,k] ----------------
// 128x128 tile, BK=32, 4 waves, global_load_lds(16B), mfma_f32_16x16x32_f16
enum { EPI_F32 = 0, EPI_F16 = 1, EPI_PROJ = 2, EPI_GELU = 3, EPI_FINAL = 4 };

template <int EPI>
__global__ __launch_bounds__(256) void gemm_nt(const f16* __restrict__ A,
                                               const f16* __restrict__ B, int K,
                                               void* __restrict__ Cout, int ldc,
                                               const float* __restrict__ bias,
                                               const float* __restrict__ res) {
  __shared__ f16 As[128 * 32];
  __shared__ f16 Bs[128 * 32];
  const int tid = threadIdx.x;
  const int wid = tid >> 6, lane = tid & 63;
  const int wm = (wid >> 1) * 64, wn = (wid & 1) * 64;
  const int lr = lane & 15, lk = (lane >> 4) * 8;
  const long bm = (long)blockIdx.y * 128, bn = (long)blockIdx.x * 128;

  f32x4 zero = {0.f, 0.f, 0.f, 0.f};
  f32x4 acc[4][4];
#pragma unroll
  for (int i = 0; i < 4; i++)
#pragma unroll
    for (int j = 0; j < 4; j++) acc[i][j] = zero;

  const f16* Arow = A + bm * K;
  const f16* Brow = B + bn * K;
  const int nkt = K >> 5;
  for (int kt = 0; kt < nkt; ++kt) {
    const int k0 = kt << 5;
    __syncthreads();
#pragma unroll
    for (int rr = 0; rr < 2; ++rr) {
      int e = rr * 256 + tid;
      g2l16(Arow + (long)(e >> 2) * K + k0 + (e & 3) * 8, &As[e * 8]);
    }
#pragma unroll
    for (int rr = 0; rr < 2; ++rr) {
      int e = rr * 256 + tid;
      g2l16(Brow + (long)(e >> 2) * K + k0 + (e & 3) * 8, &Bs[e * 8]);
    }
    __syncthreads();
    f16x8 av[4], bv[4];
#pragma unroll
    for (int i = 0; i < 4; i++) av[i] = *(const f16x8*)&As[(wm + i * 16 + lr) * 32 + lk];
#pragma unroll
    for (int i = 0; i < 4; i++) bv[i] = *(const f16x8*)&Bs[(wn + i * 16 + lr) * 32 + lk];
#pragma unroll
    for (int i = 0; i < 4; i++)
#pragma unroll
      for (int j = 0; j < 4; j++)
        acc[i][j] = __builtin_amdgcn_mfma_f32_16x16x32_f16(av[i], bv[j], acc[i][j], 0, 0, 0);
  }

  const int r0 = (int)bm + wm + (lane >> 4) * 4;
  const int c0 = (int)bn + wn + (lane & 15);
#pragma unroll
  for (int i = 0; i < 4; i++) {
#pragma unroll
    for (int j = 0; j < 4; j++) {
      const int c = c0 + j * 16;
      float bcol = 0.f;
      if (EPI == EPI_PROJ || EPI == EPI_GELU || EPI == EPI_FINAL) bcol = bias[c];
#pragma unroll
      for (int q = 0; q < 4; q++) {
        const int r = r0 + i * 16 + q;
        const long idx = (long)r * ldc + c;
        const float v = acc[i][j][q];
        if (EPI == EPI_F32) {
          ((float*)Cout)[idx] = v;
        } else if (EPI == EPI_F16) {
          ((f16*)Cout)[idx] = (f16)v;
        } else if (EPI == EPI_PROJ || EPI == EPI_FINAL) {
          ((float*)Cout)[idx] = v + bcol + res[idx];
        } else {  // EPI_GELU: exact gelu
          const float h = v + bcol;
          const float gg = 0.5f * h * (1.f + erff(h * 0.70710678118654752f));
          ((f16*)Cout)[idx] = (f16)gg;
        }
      }
    }
  }
}

// ---------------- host ----------------
extern "C" void kernel_launch(void* const* d_in, const int* in_sizes, int n_in,
                              void* d_out, int out_size, void* d_ws, size_t ws_size,
                              hipStream_t stream) {
  const float* x = (const float*)d_in[0];
  const float* x_encoder = (const float*)d_in[1];
  const float* pos = (const float*)d_in[2];
  const float* query_pos = (const float*)d_in[3];
  const float* Wp_sa = (const float*)d_in[4];
  const float* bp_sa = (const float*)d_in[5];
  const float* Wp_ca = (const float*)d_in[6];
  const float* bp_ca = (const float*)d_in[7];
  const float* W1 = (const float*)d_in[8];
  const float* b1 = (const float*)d_in[9];
  const float* W2 = (const float*)d_in[10];
  const float* b2 = (const float*)d_in[11];
  const float* g_sa = (const float*)d_in[12];
  const float* be_sa = (const float*)d_in[13];
  const float* g_ca = (const float*)d_in[14];
  const float* be_ca = (const float*)d_in[15];
  const float* g_ff = (const float*)d_in[16];
  const float* be_ff = (const float*)d_in[17];

  const size_t MB = 1024 * 1024;
  char* ws = (char*)d_ws;
  f16* wpsa16 = (f16*)(ws + 0 * MB);
  f16* wpca16 = (f16*)(ws + 2 * MB);
  f16* w116 = (f16*)(ws + 4 * MB);
  f16* w216 = (f16*)(ws + 12 * MB);
  f16* q16 = (f16*)(ws + 20 * MB);   // qk / q2 / n3
  f16* k16 = (f16*)(ws + 28 * MB);   // cross K
  f16* n16 = (f16*)(ws + 36 * MB);   // n1 / xe16
  f16* vT = (f16*)(ws + 44 * MB);    // V^T [1024][4096]
  f16* o16 = (f16*)(ws + 52 * MB);   // attn out
  float* x1 = (float*)(ws + 60 * MB);
  float* x2 = (float*)(ws + 76 * MB);
  float* scores = (float*)(ws + 92 * MB);  // 64MB fp32
  f16* h16 = (f16*)(ws + 92 * MB);         // reuses scores region after attn
  f16* P16 = (f16*)(ws + 156 * MB);        // 32MB fp16

  if (ws_size < (size_t)188 * MB) {
    fprintf(stderr, "kernel_launch: ws too small (%zu bytes, need %zu)\n", ws_size,
            (size_t)188 * MB);
    return;
  }

  // weight converts
  cvt_f32_f16<<<1024, 256, 0, stream>>>(Wp_sa, wpsa16, (long)DMODEL * DMODEL / 4);
  cvt_f32_f16<<<1024, 256, 0, stream>>>(Wp_ca, wpca16, (long)DMODEL * DMODEL / 4);
  cvt_f32_f16<<<2048, 256, 0, stream>>>(W1, w116, (long)DFF_ * DMODEL / 4);
  cvt_f32_f16<<<2048, 256, 0, stream>>>(W2, w216, (long)DMODEL * DFF_ / 4);

  // ---- self attention ----
  ln_row<<<NROW, 256, 0, stream>>>(x, g_sa, be_sa, pos, n16, q16);
  transpose_h<<<dim3(DMODEL / 64, NROW / 64), 256, 0, stream>>>(n16, vT, NROW, DMODEL);
  gemm_nt<EPI_F32><<<dim3(32, 32), 256, 0, stream>>>(q16, q16, DMODEL, scores, NROW,
                                                     nullptr, nullptr);
  softmax_row<<<NROW, 256, 0, stream>>>(scores, P16);
  gemm_nt<EPI_F16><<<dim3(8, 32), 256, 0, stream>>>(P16, vT, NROW, o16, DMODEL, nullptr,
                                                    nullptr);
  gemm_nt<EPI_PROJ><<<dim3(8, 32), 256, 0, stream>>>(o16, wpsa16, DMODEL, x1, DMODEL,
                                                     bp_sa, x);

  // ---- cross attention ----
  ln_row<<<NROW, 256, 0, stream>>>(x1, g_ca, be_ca, query_pos, nullptr, q16);
  add_cvt<<<2048, 256, 0, stream>>>(x_encoder, pos, k16, n16, (long)NROW * DMODEL / 4);
  transpose_h<<<dim3(DMODEL / 64, NROW / 64), 256, 0, stream>>>(n16, vT, NROW, DMODEL);
  gemm_nt<EPI_F32><<<dim3(32, 32), 256, 0, stream>>>(q16, k16, DMODEL, scores, NROW,
                                                     nullptr, nullptr);
  softmax_row<<<NROW, 256, 0, stream>>>(scores, P16);
  gemm_nt<EPI_F16><<<dim3(8, 32), 256, 0, stream>>>(P16, vT, NROW, o16, DMODEL, nullptr,
                                                    nullptr);
  gemm_nt<EPI_PROJ><<<dim3(8, 32), 256, 0, stream>>>(o16, wpca16, DMODEL, x2, DMODEL,
                                                     bp_ca, x1);

  // ---- feed-forward ----
  ln_row<<<NROW, 256, 0, stream>>>(x2, g_ff, be_ff, nullptr, nullptr, q16);
  gemm_nt<EPI_GELU><<<dim3(32, 32), 256, 0, stream>>>(q16, w116, DMODEL, h16, DFF_, b1,
                                                      nullptr);
  gemm_nt<EPI_FINAL><<<dim3(8, 32), 256, 0, stream>>>(h16, w216, DFF_, (float*)d_out,
                                                      DMODEL, b2, x2);
}

// Round 3
// 523.282 us; speedup vs baseline: 1.1306x; 1.1306x over previous
//
#include <hip/hip_runtime.h>
#include <hip/hip_fp16.h>
#include <cstdint>
#include <cstdio>

#define NROW 4096
#define DMODEL 1024
#define DFF_ 4096

typedef _Float16 f16;
typedef _Float16 f16x4 __attribute__((ext_vector_type(4)));
typedef _Float16 f16x8 __attribute__((ext_vector_type(8)));
typedef float f32x4 __attribute__((ext_vector_type(4)));

__device__ __forceinline__ void g2l16(const void* g, void* l) {
  __builtin_amdgcn_global_load_lds((const __attribute__((address_space(1))) void*)g,
                                   (__attribute__((address_space(3))) void*)l,
                                   16, 0, 0);
}

// ---------------- elementwise converts ----------------
__global__ __launch_bounds__(256) void cvt_f32_f16(const float* __restrict__ in,
                                                   f16* __restrict__ out, long n4) {
  for (long i = (long)blockIdx.x * blockDim.x + threadIdx.x; i < n4;
       i += (long)gridDim.x * blockDim.x) {
    float4 a = ((const float4*)in)[i];
    f16x4 h = {(f16)a.x, (f16)a.y, (f16)a.z, (f16)a.w};
    ((f16x4*)out)[i] = h;
  }
}

// k16 = f16(xe + pos); xe16 = f16(xe)
__global__ __launch_bounds__(256) void add_cvt(const float* __restrict__ xe,
                                               const float* __restrict__ pos,
                                               f16* __restrict__ k16,
                                               f16* __restrict__ xe16, long n4) {
  for (long i = (long)blockIdx.x * blockDim.x + threadIdx.x; i < n4;
       i += (long)gridDim.x * blockDim.x) {
    float4 a = ((const float4*)xe)[i];
    float4 p = ((const float4*)pos)[i];
    f16x4 k = {(f16)(a.x + p.x), (f16)(a.y + p.y), (f16)(a.z + p.z), (f16)(a.w + p.w)};
    f16x4 v = {(f16)a.x, (f16)a.y, (f16)a.z, (f16)a.w};
    ((f16x4*)k16)[i] = k;
    ((f16x4*)xe16)[i] = v;
  }
}

// ---------------- layernorm (one block per row of 1024) ----------------
__global__ __launch_bounds__(256) void ln_row(const float* __restrict__ x,
                                              const float* __restrict__ g,
                                              const float* __restrict__ b,
                                              const float* __restrict__ pos,
                                              f16* __restrict__ nout,
                                              f16* __restrict__ qout) {
  const int row = blockIdx.x, tid = threadIdx.x;
  const float4 xv = ((const float4*)(x + (long)row * DMODEL))[tid];
  float s = xv.x + xv.y + xv.z + xv.w;
  float ss = xv.x * xv.x + xv.y * xv.y + xv.z * xv.z + xv.w * xv.w;
  for (int o = 32; o; o >>= 1) { s += __shfl_xor(s, o); ss += __shfl_xor(ss, o); }
  __shared__ float rs[4], rss[4];
  const int wid = tid >> 6, lane = tid & 63;
  if (!lane) { rs[wid] = s; rss[wid] = ss; }
  __syncthreads();
  s = rs[0] + rs[1] + rs[2] + rs[3];
  ss = rss[0] + rss[1] + rss[2] + rss[3];
  const float mean = s * (1.f / DMODEL);
  const float var = ss * (1.f / DMODEL) - mean * mean;
  const float rstd = rsqrtf(var + 1e-5f);
  const float4 gv = ((const float4*)g)[tid];
  const float4 bv = ((const float4*)b)[tid];
  float4 nv;
  nv.x = (xv.x - mean) * rstd * gv.x + bv.x;
  nv.y = (xv.y - mean) * rstd * gv.y + bv.y;
  nv.z = (xv.z - mean) * rstd * gv.z + bv.z;
  nv.w = (xv.w - mean) * rstd * gv.w + bv.w;
  if (nout) {
    f16x4 h = {(f16)nv.x, (f16)nv.y, (f16)nv.z, (f16)nv.w};
    *(f16x4*)&nout[(long)row * DMODEL + tid * 4] = h;
  }
  float4 pv = {0.f, 0.f, 0.f, 0.f};
  if (pos) pv = ((const float4*)(pos + (long)row * DMODEL))[tid];
  f16x4 q = {(f16)(nv.x + pv.x), (f16)(nv.y + pv.y), (f16)(nv.z + pv.z), (f16)(nv.w + pv.w)};
  *(f16x4*)&qout[(long)row * DMODEL + tid * 4] = q;
}

// ---------------- row softmax (4096 cols), fp32 in -> fp16 out ----------------
__global__ __launch_bounds__(256) void softmax_row(const float* __restrict__ S,
                                                   f16* __restrict__ P) {
  const int row = blockIdx.x, tid = threadIdx.x;
  const float4* Sr = (const float4*)(S + (long)row * NROW);
  float4 v[4];
  float m = -1e30f;
#pragma unroll
  for (int i = 0; i < 4; i++) {
    v[i] = Sr[tid + i * 256];
    m = fmaxf(m, fmaxf(fmaxf(v[i].x, v[i].y), fmaxf(v[i].z, v[i].w)));
  }
  for (int o = 32; o; o >>= 1) m = fmaxf(m, __shfl_xor(m, o));
  __shared__ float red[4], red2[4];
  const int wid = tid >> 6, lane = tid & 63;
  if (!lane) red[wid] = m;
  __syncthreads();
  m = fmaxf(fmaxf(red[0], red[1]), fmaxf(red[2], red[3]));
  float sum = 0.f;
#pragma unroll
  for (int i = 0; i < 4; i++) {
    v[i].x = __expf(v[i].x - m); v[i].y = __expf(v[i].y - m);
    v[i].z = __expf(v[i].z - m); v[i].w = __expf(v[i].w - m);
    sum += v[i].x + v[i].y + v[i].z + v[i].w;
  }
  for (int o = 32; o; o >>= 1) sum += __shfl_xor(sum, o);
  if (!lane) red2[wid] = sum;
  __syncthreads();
  sum = red2[0] + red2[1] + red2[2] + red2[3];
  const float r = 1.f / sum;
  f16* Pr = P + (long)row * NROW;
#pragma unroll
  for (int i = 0; i < 4; i++) {
    f16x4 h = {(f16)(v[i].x * r), (f16)(v[i].y * r), (f16)(v[i].z * r), (f16)(v[i].w * r)};
    *(f16x4*)&Pr[(tid + i * 256) * 4] = h;
  }
}

// ---------------- fp16 transpose: in [R][C] -> out [C][R], 64x64 tiles ----------------
__global__ __launch_bounds__(256) void transpose_h(const f16* __restrict__ in,
                                                   f16* __restrict__ out, int R, int C) {
  __shared__ f16 t[64][72];
  const int tid = threadIdx.x;
  const int r0 = blockIdx.y * 64, c0 = blockIdx.x * 64;
  const int tr = tid >> 4, tc = (tid & 15) * 4;
#pragma unroll
  for (int rr = 0; rr < 4; rr++) {
    int row = rr * 16 + tr;
    f16x4 v = *(const f16x4*)&in[(long)(r0 + row) * C + c0 + tc];
    *(f16x4*)&t[row][tc] = v;
  }
  __syncthreads();
#pragma unroll
  for (int rr = 0; rr < 4; rr++) {
    int row = rr * 16 + tr;
    f16x4 o = {t[tc + 0][row], t[tc + 1][row], t[tc + 2][row], t[tc + 3][row]};
    *(f16x4*)&out[(long)(c0 + row) * R + r0 + tc] = o;
  }
}

// ---------------- NT GEMM: C[m,n] = sum_k A[m,k]*B[n,k] ----------------
// BM=128 fixed, BN in {64,128}. 4 waves (2x2). BK=32. global_load_lds(16B).
// 2D grid (no swizzle). Staging pinned between barriers with sched_barrier(0).
enum { EPI_F32 = 0, EPI_F16 = 1, EPI_PROJ = 2, EPI_GELU = 3, EPI_FINAL = 4 };

template <int EPI, int BN>
__global__ __launch_bounds__(256) void gemm_nt(const f16* __restrict__ A,
                                               const f16* __restrict__ B, int K,
                                               void* __restrict__ Cout, int ldc,
                                               const float* __restrict__ bias,
                                               const float* __restrict__ res) {
  constexpr int NJ = BN / 32;  // 16-wide B frags per wave
  __shared__ f16 As[128 * 32];
  __shared__ f16 Bs[BN * 32];
  const int tid = threadIdx.x;
  const int wid = tid >> 6, lane = tid & 63;
  const int wm = (wid >> 1) * 64, wn = (wid & 1) * (BN / 2);
  const int lr = lane & 15, lk = (lane >> 4) * 8;
  const long bm = (long)blockIdx.y * 128;
  const long bn = (long)blockIdx.x * BN;

  f32x4 zero = {0.f, 0.f, 0.f, 0.f};
  f32x4 acc[4][NJ];
#pragma unroll
  for (int i = 0; i < 4; i++)
#pragma unroll
    for (int j = 0; j < NJ; j++) acc[i][j] = zero;

  const f16* Arow = A + bm * K;
  const f16* Brow = B + bn * K;
  const int nkt = K >> 5;
  for (int kt = 0; kt < nkt; ++kt) {
    const int k0 = kt << 5;
    __syncthreads();
    __builtin_amdgcn_sched_barrier(0);
#pragma unroll
    for (int rr = 0; rr < 2; ++rr) {
      int e = rr * 256 + tid;
      g2l16(Arow + (long)(e >> 2) * K + k0 + (e & 3) * 8, &As[e * 8]);
    }
#pragma unroll
    for (int rr = 0; rr < BN / 64; ++rr) {
      int e = rr * 256 + tid;
      g2l16(Brow + (long)(e >> 2) * K + k0 + (e & 3) * 8, &Bs[e * 8]);
    }
    __builtin_amdgcn_sched_barrier(0);
    __syncthreads();
    f16x8 av[4], bv[NJ];
#pragma unroll
    for (int i = 0; i < 4; i++) av[i] = *(const f16x8*)&As[(wm + i * 16 + lr) * 32 + lk];
#pragma unroll
    for (int j = 0; j < NJ; j++) bv[j] = *(const f16x8*)&Bs[(wn + j * 16 + lr) * 32 + lk];
#pragma unroll
    for (int i = 0; i < 4; i++)
#pragma unroll
      for (int j = 0; j < NJ; j++)
        acc[i][j] = __builtin_amdgcn_mfma_f32_16x16x32_f16(av[i], bv[j], acc[i][j], 0, 0, 0);
  }

  const int r0 = (int)bm + wm + (lane >> 4) * 4;
  const int c0 = (int)bn + wn + (lane & 15);
#pragma unroll
  for (int i = 0; i < 4; i++) {
#pragma unroll
    for (int j = 0; j < NJ; j++) {
      const int c = c0 + j * 16;
      float bcol = 0.f;
      if (EPI == EPI_PROJ || EPI == EPI_GELU || EPI == EPI_FINAL) bcol = bias[c];
#pragma unroll
      for (int q = 0; q < 4; q++) {
        const int r = r0 + i * 16 + q;
        const long idx = (long)r * ldc + c;
        const float v = acc[i][j][q];
        if (EPI == EPI_F32) {
          ((float*)Cout)[idx] = v;
        } else if (EPI == EPI_F16) {
          ((f16*)Cout)[idx] = (f16)v;
        } else if (EPI == EPI_PROJ || EPI == EPI_FINAL) {
          ((float*)Cout)[idx] = v + bcol + res[idx];
        } else {  // EPI_GELU: exact gelu
          const float h = v + bcol;
          const float gg = 0.5f * h * (1.f + erff(h * 0.70710678118654752f));
          ((f16*)Cout)[idx] = (f16)gg;
        }
      }
    }
  }
}

// ---------------- host ----------------
extern "C" void kernel_launch(void* const* d_in, const int* in_sizes, int n_in,
                              void* d_out, int out_size, void* d_ws, size_t ws_size,
                              hipStream_t stream) {
  const float* x = (const float*)d_in[0];
  const float* x_encoder = (const float*)d_in[1];
  const float* pos = (const float*)d_in[2];
  const float* query_pos = (const float*)d_in[3];
  const float* Wp_sa = (const float*)d_in[4];
  const float* bp_sa = (const float*)d_in[5];
  const float* Wp_ca = (const float*)d_in[6];
  const float* bp_ca = (const float*)d_in[7];
  const float* W1 = (const float*)d_in[8];
  const float* b1 = (const float*)d_in[9];
  const float* W2 = (const float*)d_in[10];
  const float* b2 = (const float*)d_in[11];
  const float* g_sa = (const float*)d_in[12];
  const float* be_sa = (const float*)d_in[13];
  const float* g_ca = (const float*)d_in[14];
  const float* be_ca = (const float*)d_in[15];
  const float* g_ff = (const float*)d_in[16];
  const float* be_ff = (const float*)d_in[17];

  const size_t MB = 1024 * 1024;
  char* ws = (char*)d_ws;
  f16* wpsa16 = (f16*)(ws + 0 * MB);
  f16* wpca16 = (f16*)(ws + 2 * MB);
  f16* w116 = (f16*)(ws + 4 * MB);
  f16* w216 = (f16*)(ws + 12 * MB);
  f16* q16 = (f16*)(ws + 20 * MB);   // qk / q2 / n3
  f16* k16 = (f16*)(ws + 28 * MB);   // cross K
  f16* n16 = (f16*)(ws + 36 * MB);   // n1 / xe16
  f16* vT = (f16*)(ws + 44 * MB);    // V^T [1024][4096]
  f16* o16 = (f16*)(ws + 52 * MB);   // attn out
  float* x1 = (float*)(ws + 60 * MB);
  float* x2 = (float*)(ws + 76 * MB);
  float* scores = (float*)(ws + 92 * MB);  // 64MB fp32
  f16* h16 = (f16*)(ws + 92 * MB);         // reuses scores region after attn
  f16* P16 = (f16*)(ws + 156 * MB);        // 32MB fp16

  if (ws_size < (size_t)188 * MB) {
    fprintf(stderr, "kernel_launch: ws too small (%zu bytes, need %zu)\n", ws_size,
            (size_t)188 * MB);
    return;
  }

  // weight converts
  cvt_f32_f16<<<1024, 256, 0, stream>>>(Wp_sa, wpsa16, (long)DMODEL * DMODEL / 4);
  cvt_f32_f16<<<1024, 256, 0, stream>>>(Wp_ca, wpca16, (long)DMODEL * DMODEL / 4);
  cvt_f32_f16<<<2048, 256, 0, stream>>>(W1, w116, (long)DFF_ * DMODEL / 4);
  cvt_f32_f16<<<2048, 256, 0, stream>>>(W2, w216, (long)DMODEL * DFF_ / 4);

  // ---- self attention ----
  ln_row<<<NROW, 256, 0, stream>>>(x, g_sa, be_sa, pos, n16, q16);
  transpose_h<<<dim3(DMODEL / 64, NROW / 64), 256, 0, stream>>>(n16, vT, NROW, DMODEL);
  gemm_nt<EPI_F32, 128><<<dim3(32, 32), 256, 0, stream>>>(q16, q16, DMODEL, scores, NROW,
                                                          nullptr, nullptr);
  softmax_row<<<NROW, 256, 0, stream>>>(scores, P16);
  gemm_nt<EPI_F16, 64><<<dim3(16, 32), 256, 0, stream>>>(P16, vT, NROW, o16, DMODEL,
                                                         nullptr, nullptr);
  gemm_nt<EPI_PROJ, 64><<<dim3(16, 32), 256, 0, stream>>>(o16, wpsa16, DMODEL, x1, DMODEL,
                                                          bp_sa, x);

  // ---- cross attention ----
  ln_row<<<NROW, 256, 0, stream>>>(x1, g_ca, be_ca, query_pos, nullptr, q16);
  add_cvt<<<2048, 256, 0, stream>>>(x_encoder, pos, k16, n16, (long)NROW * DMODEL / 4);
  transpose_h<<<dim3(DMODEL / 64, NROW / 64), 256, 0, stream>>>(n16, vT, NROW, DMODEL);
  gemm_nt<EPI_F32, 128><<<dim3(32, 32), 256, 0, stream>>>(q16, k16, DMODEL, scores, NROW,
                                                          nullptr, nullptr);
  softmax_row<<<NROW, 256, 0, stream>>>(scores, P16);
  gemm_nt<EPI_F16, 64><<<dim3(16, 32), 256, 0, stream>>>(P16, vT, NROW, o16, DMODEL,
                                                         nullptr, nullptr);
  gemm_nt<EPI_PROJ, 64><<<dim3(16, 32), 256, 0, stream>>>(o16, wpca16, DMODEL, x2, DMODEL,
                                                          bp_ca, x1);

  // ---- feed-forward ----
  ln_row<<<NROW, 256, 0, stream>>>(x2, g_ff, be_ff, nullptr, nullptr, q16);
  gemm_nt<EPI_GELU, 128><<<dim3(32, 32), 256, 0, stream>>>(q16, w116, DMODEL, h16, DFF_,
                                                           b1, nullptr);
  gemm_nt<EPI_FINAL, 64><<<dim3(16, 32), 256, 0, stream>>>(h16, w216, DFF_, (float*)d_out,
                                                           DMODEL, b2, x2);
}

// Round 4
// 485.285 us; speedup vs baseline: 1.2191x; 1.0783x over previous
//
#include <hip/hip_runtime.h>
#include <hip/hip_fp16.h>
#include <cstdint>
#include <cstdio>

#define NROW 4096
#define DMODEL 1024
#define DFF_ 4096

typedef _Float16 f16;
typedef _Float16 f16x4 __attribute__((ext_vector_type(4)));
typedef _Float16 f16x8 __attribute__((ext_vector_type(8)));
typedef float f32x4 __attribute__((ext_vector_type(4)));

__device__ __forceinline__ void g2l16(const void* g, void* l) {
  __builtin_amdgcn_global_load_lds((const __attribute__((address_space(1))) void*)g,
                                   (__attribute__((address_space(3))) void*)l,
                                   16, 0, 0);
}

// ---------------- elementwise converts ----------------
__global__ __launch_bounds__(256) void cvt_f32_f16(const float* __restrict__ in,
                                                   f16* __restrict__ out, long n4) {
  for (long i = (long)blockIdx.x * blockDim.x + threadIdx.x; i < n4;
       i += (long)gridDim.x * blockDim.x) {
    float4 a = ((const float4*)in)[i];
    f16x4 h = {(f16)a.x, (f16)a.y, (f16)a.z, (f16)a.w};
    ((f16x4*)out)[i] = h;
  }
}

// k16 = f16(xe + pos); xe16 = f16(xe)
__global__ __launch_bounds__(256) void add_cvt(const float* __restrict__ xe,
                                               const float* __restrict__ pos,
                                               f16* __restrict__ k16,
                                               f16* __restrict__ xe16, long n4) {
  for (long i = (long)blockIdx.x * blockDim.x + threadIdx.x; i < n4;
       i += (long)gridDim.x * blockDim.x) {
    float4 a = ((const float4*)xe)[i];
    float4 p = ((const float4*)pos)[i];
    f16x4 k = {(f16)(a.x + p.x), (f16)(a.y + p.y), (f16)(a.z + p.z), (f16)(a.w + p.w)};
    f16x4 v = {(f16)a.x, (f16)a.y, (f16)a.z, (f16)a.w};
    ((f16x4*)k16)[i] = k;
    ((f16x4*)xe16)[i] = v;
  }
}

// ---------------- layernorm (one block per row of 1024) ----------------
__global__ __launch_bounds__(256) void ln_row(const float* __restrict__ x,
                                              const float* __restrict__ g,
                                              const float* __restrict__ b,
                                              const float* __restrict__ pos,
                                              f16* __restrict__ nout,
                                              f16* __restrict__ qout) {
  const int row = blockIdx.x, tid = threadIdx.x;
  const float4 xv = ((const float4*)(x + (long)row * DMODEL))[tid];
  float s = xv.x + xv.y + xv.z + xv.w;
  float ss = xv.x * xv.x + xv.y * xv.y + xv.z * xv.z + xv.w * xv.w;
  for (int o = 32; o; o >>= 1) { s += __shfl_xor(s, o); ss += __shfl_xor(ss, o); }
  __shared__ float rs[4], rss[4];
  const int wid = tid >> 6, lane = tid & 63;
  if (!lane) { rs[wid] = s; rss[wid] = ss; }
  __syncthreads();
  s = rs[0] + rs[1] + rs[2] + rs[3];
  ss = rss[0] + rss[1] + rss[2] + rss[3];
  const float mean = s * (1.f / DMODEL);
  const float var = ss * (1.f / DMODEL) - mean * mean;
  const float rstd = rsqrtf(var + 1e-5f);
  const float4 gv = ((const float4*)g)[tid];
  const float4 bv = ((const float4*)b)[tid];
  float4 nv;
  nv.x = (xv.x - mean) * rstd * gv.x + bv.x;
  nv.y = (xv.y - mean) * rstd * gv.y + bv.y;
  nv.z = (xv.z - mean) * rstd * gv.z + bv.z;
  nv.w = (xv.w - mean) * rstd * gv.w + bv.w;
  if (nout) {
    f16x4 h = {(f16)nv.x, (f16)nv.y, (f16)nv.z, (f16)nv.w};
    *(f16x4*)&nout[(long)row * DMODEL + tid * 4] = h;
  }
  float4 pv = {0.f, 0.f, 0.f, 0.f};
  if (pos) pv = ((const float4*)(pos + (long)row * DMODEL))[tid];
  f16x4 q = {(f16)(nv.x + pv.x), (f16)(nv.y + pv.y), (f16)(nv.z + pv.z), (f16)(nv.w + pv.w)};
  *(f16x4*)&qout[(long)row * DMODEL + tid * 4] = q;
}

// ---------------- row softmax (4096 cols), fp32 in -> fp16 out ----------------
__global__ __launch_bounds__(256) void softmax_row(const float* __restrict__ S,
                                                   f16* __restrict__ P) {
  const int row = blockIdx.x, tid = threadIdx.x;
  const float4* Sr = (const float4*)(S + (long)row * NROW);
  float4 v[4];
  float m = -1e30f;
#pragma unroll
  for (int i = 0; i < 4; i++) {
    v[i] = Sr[tid + i * 256];
    m = fmaxf(m, fmaxf(fmaxf(v[i].x, v[i].y), fmaxf(v[i].z, v[i].w)));
  }
  for (int o = 32; o; o >>= 1) m = fmaxf(m, __shfl_xor(m, o));
  __shared__ float red[4], red2[4];
  const int wid = tid >> 6, lane = tid & 63;
  if (!lane) red[wid] = m;
  __syncthreads();
  m = fmaxf(fmaxf(red[0], red[1]), fmaxf(red[2], red[3]));
  float sum = 0.f;
#pragma unroll
  for (int i = 0; i < 4; i++) {
    v[i].x = __expf(v[i].x - m); v[i].y = __expf(v[i].y - m);
    v[i].z = __expf(v[i].z - m); v[i].w = __expf(v[i].w - m);
    sum += v[i].x + v[i].y + v[i].z + v[i].w;
  }
  for (int o = 32; o; o >>= 1) sum += __shfl_xor(sum, o);
  if (!lane) red2[wid] = sum;
  __syncthreads();
  sum = red2[0] + red2[1] + red2[2] + red2[3];
  const float r = 1.f / sum;
  f16* Pr = P + (long)row * NROW;
#pragma unroll
  for (int i = 0; i < 4; i++) {
    f16x4 h = {(f16)(v[i].x * r), (f16)(v[i].y * r), (f16)(v[i].z * r), (f16)(v[i].w * r)};
    *(f16x4*)&Pr[(tid + i * 256) * 4] = h;
  }
}

// ---------------- fp16 transpose: in [R][C] -> out [C][R], 64x64 tiles ----------------
__global__ __launch_bounds__(256) void transpose_h(const f16* __restrict__ in,
                                                   f16* __restrict__ out, int R, int C) {
  __shared__ f16 t[64][72];
  const int tid = threadIdx.x;
  const int r0 = blockIdx.y * 64, c0 = blockIdx.x * 64;
  const int tr = tid >> 4, tc = (tid & 15) * 4;
#pragma unroll
  for (int rr = 0; rr < 4; rr++) {
    int row = rr * 16 + tr;
    f16x4 v = *(const f16x4*)&in[(long)(r0 + row) * C + c0 + tc];
    *(f16x4*)&t[row][tc] = v;
  }
  __syncthreads();
#pragma unroll
  for (int rr = 0; rr < 4; rr++) {
    int row = rr * 16 + tr;
    f16x4 o = {t[tc + 0][row], t[tc + 1][row], t[tc + 2][row], t[tc + 3][row]};
    *(f16x4*)&out[(long)(c0 + row) * R + r0 + tc] = o;
  }
}

// ---------------- NT GEMM: C[m,n] = sum_k A[m,k]*B[n,k] ----------------
// BM=128, BN in {64,128}. 4 waves (2x2). BK=32. global_load_lds(16B).
// 2-phase double-buffered pipeline: stage tile t+1 (async) || compute tile t;
// one full-drain __syncthreads() per K-step (its vmcnt(0) completes the stage).
// Buffers are distinct named __shared__ arrays -> compiler-provable non-alias.
enum { EPI_F32 = 0, EPI_F16 = 1, EPI_PROJ = 2, EPI_GELU = 3, EPI_FINAL = 4 };

template <int BN>
__device__ __forceinline__ void stage_tile(const f16* __restrict__ Arow,
                                           const f16* __restrict__ Brow, int K, int kt,
                                           int tid, f16* Asd, f16* Bsd) {
  const int k0 = kt << 5;
#pragma unroll
  for (int rr = 0; rr < 2; ++rr) {
    int e = rr * 256 + tid;
    g2l16(Arow + (long)(e >> 2) * K + k0 + (e & 3) * 8, Asd + e * 8);
  }
#pragma unroll
  for (int rr = 0; rr < BN / 64; ++rr) {
    int e = rr * 256 + tid;
    g2l16(Brow + (long)(e >> 2) * K + k0 + (e & 3) * 8, Bsd + e * 8);
  }
  // pin issue order: all staging loads issued before subsequent ds_read/MFMA
  __builtin_amdgcn_sched_barrier(0);
}

template <int NJ>
__device__ __forceinline__ void compute_tile(const f16* Asd, const f16* Bsd, int wm,
                                             int wn, int lr, int lk,
                                             f32x4 (&acc)[4][NJ]) {
  f16x8 av[4], bv[NJ];
#pragma unroll
  for (int i = 0; i < 4; i++) av[i] = *(const f16x8*)&Asd[(wm + i * 16 + lr) * 32 + lk];
#pragma unroll
  for (int j = 0; j < NJ; j++) bv[j] = *(const f16x8*)&Bsd[(wn + j * 16 + lr) * 32 + lk];
#pragma unroll
  for (int i = 0; i < 4; i++)
#pragma unroll
    for (int j = 0; j < NJ; j++)
      acc[i][j] = __builtin_amdgcn_mfma_f32_16x16x32_f16(av[i], bv[j], acc[i][j], 0, 0, 0);
}

template <int EPI, int BN>
__global__ __launch_bounds__(256) void gemm_nt(const f16* __restrict__ A,
                                               const f16* __restrict__ B, int K,
                                               void* __restrict__ Cout, int ldc,
                                               const float* __restrict__ bias,
                                               const float* __restrict__ res) {
  constexpr int NJ = BN / 32;  // 16-wide B frags per wave
  __shared__ f16 As0[128 * 32];
  __shared__ f16 As1[128 * 32];
  __shared__ f16 Bs0[BN * 32];
  __shared__ f16 Bs1[BN * 32];
  const int tid = threadIdx.x;
  const int wid = tid >> 6, lane = tid & 63;
  const int wm = (wid >> 1) * 64, wn = (wid & 1) * (BN / 2);
  const int lr = lane & 15, lk = (lane >> 4) * 8;
  const long bm = (long)blockIdx.y * 128;
  const long bn = (long)blockIdx.x * BN;

  f32x4 zero = {0.f, 0.f, 0.f, 0.f};
  f32x4 acc[4][NJ];
#pragma unroll
  for (int i = 0; i < 4; i++)
#pragma unroll
    for (int j = 0; j < NJ; j++) acc[i][j] = zero;

  const f16* Arow = A + bm * K;
  const f16* Brow = B + bn * K;
  const int nkt = K >> 5;  // always even (K in {1024, 4096})

  stage_tile<BN>(Arow, Brow, K, 0, tid, As0, Bs0);
  __syncthreads();  // vmcnt(0) drain -> buf0 ready

  int kt = 0;
  for (; kt + 2 < nkt; kt += 2) {
    stage_tile<BN>(Arow, Brow, K, kt + 1, tid, As1, Bs1);
    compute_tile<NJ>(As0, Bs0, wm, wn, lr, lk, acc);
    __syncthreads();  // drains stage of buf1; buf0 reads all complete
    stage_tile<BN>(Arow, Brow, K, kt + 2, tid, As0, Bs0);
    compute_tile<NJ>(As1, Bs1, wm, wn, lr, lk, acc);
    __syncthreads();
  }
  // kt == nkt-2: buf0 holds tile nkt-2 (synced)
  stage_tile<BN>(Arow, Brow, K, nkt - 1, tid, As1, Bs1);
  compute_tile<NJ>(As0, Bs0, wm, wn, lr, lk, acc);
  __syncthreads();
  compute_tile<NJ>(As1, Bs1, wm, wn, lr, lk, acc);

  const int r0 = (int)bm + wm + (lane >> 4) * 4;
  const int c0 = (int)bn + wn + (lane & 15);
#pragma unroll
  for (int i = 0; i < 4; i++) {
#pragma unroll
    for (int j = 0; j < NJ; j++) {
      const int c = c0 + j * 16;
      float bcol = 0.f;
      if (EPI == EPI_PROJ || EPI == EPI_GELU || EPI == EPI_FINAL) bcol = bias[c];
#pragma unroll
      for (int q = 0; q < 4; q++) {
        const int r = r0 + i * 16 + q;
        const long idx = (long)r * ldc + c;
        const float v = acc[i][j][q];
        if (EPI == EPI_F32) {
          ((float*)Cout)[idx] = v;
        } else if (EPI == EPI_F16) {
          ((f16*)Cout)[idx] = (f16)v;
        } else if (EPI == EPI_PROJ || EPI == EPI_FINAL) {
          ((float*)Cout)[idx] = v + bcol + res[idx];
        } else {  // EPI_GELU: exact gelu
          const float h = v + bcol;
          const float gg = 0.5f * h * (1.f + erff(h * 0.70710678118654752f));
          ((f16*)Cout)[idx] = (f16)gg;
        }
      }
    }
  }
}

// ---------------- host ----------------
extern "C" void kernel_launch(void* const* d_in, const int* in_sizes, int n_in,
                              void* d_out, int out_size, void* d_ws, size_t ws_size,
                              hipStream_t stream) {
  const float* x = (const float*)d_in[0];
  const float* x_encoder = (const float*)d_in[1];
  const float* pos = (const float*)d_in[2];
  const float* query_pos = (const float*)d_in[3];
  const float* Wp_sa = (const float*)d_in[4];
  const float* bp_sa = (const float*)d_in[5];
  const float* Wp_ca = (const float*)d_in[6];
  const float* bp_ca = (const float*)d_in[7];
  const float* W1 = (const float*)d_in[8];
  const float* b1 = (const float*)d_in[9];
  const float* W2 = (const float*)d_in[10];
  const float* b2 = (const float*)d_in[11];
  const float* g_sa = (const float*)d_in[12];
  const float* be_sa = (const float*)d_in[13];
  const float* g_ca = (const float*)d_in[14];
  const float* be_ca = (const float*)d_in[15];
  const float* g_ff = (const float*)d_in[16];
  const float* be_ff = (const float*)d_in[17];

  const size_t MB = 1024 * 1024;
  char* ws = (char*)d_ws;
  f16* wpsa16 = (f16*)(ws + 0 * MB);
  f16* wpca16 = (f16*)(ws + 2 * MB);
  f16* w116 = (f16*)(ws + 4 * MB);
  f16* w216 = (f16*)(ws + 12 * MB);
  f16* q16 = (f16*)(ws + 20 * MB);   // qk / q2 / n3
  f16* k16 = (f16*)(ws + 28 * MB);   // cross K
  f16* n16 = (f16*)(ws + 36 * MB);   // n1 / xe16
  f16* vT = (f16*)(ws + 44 * MB);    // V^T [1024][4096]
  f16* o16 = (f16*)(ws + 52 * MB);   // attn out
  float* x1 = (float*)(ws + 60 * MB);
  float* x2 = (float*)(ws + 76 * MB);
  float* scores = (float*)(ws + 92 * MB);  // 64MB fp32
  f16* h16 = (f16*)(ws + 92 * MB);         // reuses scores region after attn
  f16* P16 = (f16*)(ws + 156 * MB);        // 32MB fp16

  if (ws_size < (size_t)188 * MB) {
    fprintf(stderr, "kernel_launch: ws too small (%zu bytes, need %zu)\n", ws_size,
            (size_t)188 * MB);
    return;
  }

  // weight converts
  cvt_f32_f16<<<1024, 256, 0, stream>>>(Wp_sa, wpsa16, (long)DMODEL * DMODEL / 4);
  cvt_f32_f16<<<1024, 256, 0, stream>>>(Wp_ca, wpca16, (long)DMODEL * DMODEL / 4);
  cvt_f32_f16<<<2048, 256, 0, stream>>>(W1, w116, (long)DFF_ * DMODEL / 4);
  cvt_f32_f16<<<2048, 256, 0, stream>>>(W2, w216, (long)DMODEL * DFF_ / 4);

  // ---- self attention ----
  ln_row<<<NROW, 256, 0, stream>>>(x, g_sa, be_sa, pos, n16, q16);
  transpose_h<<<dim3(DMODEL / 64, NROW / 64), 256, 0, stream>>>(n16, vT, NROW, DMODEL);
  gemm_nt<EPI_F32, 128><<<dim3(32, 32), 256, 0, stream>>>(q16, q16, DMODEL, scores, NROW,
                                                          nullptr, nullptr);
  softmax_row<<<NROW, 256, 0, stream>>>(scores, P16);
  gemm_nt<EPI_F16, 64><<<dim3(16, 32), 256, 0, stream>>>(P16, vT, NROW, o16, DMODEL,
                                                         nullptr, nullptr);
  gemm_nt<EPI_PROJ, 64><<<dim3(16, 32), 256, 0, stream>>>(o16, wpsa16, DMODEL, x1, DMODEL,
                                                          bp_sa, x);

  // ---- cross attention ----
  ln_row<<<NROW, 256, 0, stream>>>(x1, g_ca, be_ca, query_pos, nullptr, q16);
  add_cvt<<<2048, 256, 0, stream>>>(x_encoder, pos, k16, n16, (long)NROW * DMODEL / 4);
  transpose_h<<<dim3(DMODEL / 64, NROW / 64), 256, 0, stream>>>(n16, vT, NROW, DMODEL);
  gemm_nt<EPI_F32, 128><<<dim3(32, 32), 256, 0, stream>>>(q16, k16, DMODEL, scores, NROW,
                                                          nullptr, nullptr);
  softmax_row<<<NROW, 256, 0, stream>>>(scores, P16);
  gemm_nt<EPI_F16, 64><<<dim3(16, 32), 256, 0, stream>>>(P16, vT, NROW, o16, DMODEL,
                                                         nullptr, nullptr);
  gemm_nt<EPI_PROJ, 64><<<dim3(16, 32), 256, 0, stream>>>(o16, wpca16, DMODEL, x2, DMODEL,
                                                          bp_ca, x1);

  // ---- feed-forward ----
  ln_row<<<NROW, 256, 0, stream>>>(x2, g_ff, be_ff, nullptr, nullptr, q16);
  gemm_nt<EPI_GELU, 128><<<dim3(32, 32), 256, 0, stream>>>(q16, w116, DMODEL, h16, DFF_,
                                                           b1, nullptr);
  gemm_nt<EPI_FINAL, 64><<<dim3(16, 32), 256, 0, stream>>>(h16, w216, DFF_, (float*)d_out,
                                                           DMODEL, b2, x2);
}